// Round 1
// baseline (278.526 us; speedup 1.0000x reference)
//
#include <hip/hip_runtime.h>

// PieceMaxPool: out[b, p*C + c] = max_l ( x[b,c,l] + (mask[b,l]==p+1 ? 0 : -100) )
// x: (B=256, C=768, L=256) fp32, mask: (B, L) int32 in [0,3], out: (B, 3*C) fp32.
// Memory-bound streaming kernel: ~201 MB read, ~2.4 MB write -> ~32 us floor at 6.3 TB/s.

constexpr int BB = 256;
constexpr int CC = 768;
constexpr int LL = 256;
constexpr int PP = 3;
constexpr float MINUS = -100.0f;

constexpr int ROWS_PER_WAVE  = 12;
constexpr int WAVES_PER_BLOCK = 4;
constexpr int ROWS_PER_BLOCK = ROWS_PER_WAVE * WAVES_PER_BLOCK;  // 48
constexpr int BLOCKS_PER_B   = CC / ROWS_PER_BLOCK;              // 16

__global__ __launch_bounds__(256) void piece_max_pool_kernel(
    const float* __restrict__ x,
    const int*   __restrict__ mask,
    float*       __restrict__ out)
{
    const int tid  = threadIdx.x;
    const int lane = tid & 63;
    const int wave = tid >> 6;
    const int blk  = blockIdx.x;
    const int b    = blk / BLOCKS_PER_B;
    const int cbase = (blk % BLOCKS_PER_B) * ROWS_PER_BLOCK + wave * ROWS_PER_WAVE;

    // Per-lane bias for l = lane*4 .. lane*4+3 (constant across all c of this b).
    const int4 m4 = *reinterpret_cast<const int4*>(mask + b * LL + lane * 4);
    const int mm[4] = {m4.x, m4.y, m4.z, m4.w};
    float bias[PP][4];
#pragma unroll
    for (int p = 0; p < PP; ++p)
#pragma unroll
        for (int j = 0; j < 4; ++j)
            bias[p][j] = (mm[j] == p + 1) ? 0.0f : MINUS;

    const float* xbase = x + ((size_t)b * CC + cbase) * LL + lane * 4;

#pragma unroll
    for (int r = 0; r < ROWS_PER_WAVE; ++r) {
        const float4 v = *reinterpret_cast<const float4*>(xbase + (size_t)r * LL);
        const float vv[4] = {v.x, v.y, v.z, v.w};

        float mx[PP];
#pragma unroll
        for (int p = 0; p < PP; ++p) {
            const float m0 = fmaxf(vv[0] + bias[p][0], vv[1] + bias[p][1]);
            const float m1 = fmaxf(vv[2] + bias[p][2], vv[3] + bias[p][3]);
            mx[p] = fmaxf(m0, m1);
        }

        // 64-lane butterfly max reduce for the 3 piece maxima.
#pragma unroll
        for (int off = 32; off >= 1; off >>= 1) {
#pragma unroll
            for (int p = 0; p < PP; ++p)
                mx[p] = fmaxf(mx[p], __shfl_xor(mx[p], off, 64));
        }

        if (lane == 0) {
            const int c = cbase + r;
            float* o = out + (size_t)b * (PP * CC) + c;
#pragma unroll
            for (int p = 0; p < PP; ++p)
                o[(size_t)p * CC] = mx[p];
        }
    }
}

extern "C" void kernel_launch(void* const* d_in, const int* in_sizes, int n_in,
                              void* d_out, int out_size, void* d_ws, size_t ws_size,
                              hipStream_t stream)
{
    const float* x    = (const float*)d_in[0];
    const int*   mask = (const int*)d_in[1];
    float*       out  = (float*)d_out;

    const int grid = BB * BLOCKS_PER_B;  // 4096 blocks
    piece_max_pool_kernel<<<grid, WAVES_PER_BLOCK * 64, 0, stream>>>(x, mask, out);
}

// Round 3
// 253.388 us; speedup vs baseline: 1.0992x; 1.0992x over previous
//
#include <hip/hip_runtime.h>

// PieceMaxPool: out[b, p*C + c] = max_l ( x[b,c,l] + (mask[b,l]==p+1 ? 0 : -100) )
// x: (B=256, C=768, L=256) fp32, mask: (B, L) int32 in [0,3], out: (B, 3*C) fp32.
// Memory-bound: ~201 MiB read -> ~31 us floor at ~6.9 TB/s.
//
// R2 = R1 design (16-lane row groups, 4 rows reduced concurrently per wave,
// 3 shfl/row instead of 18) with the nontemporal load done through a clang
// ext_vector_type float4 (HIP_vector_type is rejected by the builtin).

constexpr int BB = 256;
constexpr int CC = 768;
constexpr int LL = 256;
constexpr int PP = 3;
constexpr float MINUS = -100.0f;

typedef float f32x4 __attribute__((ext_vector_type(4)));

constexpr int QUADS_PER_WAVE  = 3;                       // 12 rows per wave
constexpr int WAVES_PER_BLOCK = 4;
constexpr int ROWS_PER_BLOCK  = 4 * QUADS_PER_WAVE * WAVES_PER_BLOCK;  // 48
constexpr int BLOCKS_PER_B    = CC / ROWS_PER_BLOCK;     // 16

__global__ __launch_bounds__(256) void piece_max_pool_kernel(
    const float* __restrict__ x,
    const int*   __restrict__ mask,
    float*       __restrict__ out)
{
    const int tid  = threadIdx.x;
    const int lane = tid & 63;
    const int g    = lane & 15;        // position within 16-lane row group
    const int rsub = lane >> 4;        // which of the 4 rows in the quad
    const int wave = tid >> 6;
    const int blk  = blockIdx.x;
    const int b    = blk / BLOCKS_PER_B;
    // first row of this wave's 3 quads
    const int cbase = (blk % BLOCKS_PER_B) * ROWS_PER_BLOCK + wave * (4 * QUADS_PER_WAVE);

    // ---- per-lane bias for its 16 l-positions: l = j*64 + g*4 + k ----
    // identical for all rows of this b; computed once, reused for 12 rows.
    float bias[PP][16];
#pragma unroll
    for (int j = 0; j < 4; ++j) {
        const int4 m4 = *reinterpret_cast<const int4*>(mask + b * LL + j * 64 + g * 4);
        const int mm[4] = {m4.x, m4.y, m4.z, m4.w};
#pragma unroll
        for (int p = 0; p < PP; ++p)
#pragma unroll
            for (int k = 0; k < 4; ++k)
                bias[p][j * 4 + k] = (mm[k] == p + 1) ? 0.0f : MINUS;
    }

#pragma unroll
    for (int q = 0; q < QUADS_PER_WAVE; ++q) {
        const int c = cbase + q * 4 + rsub;               // this lane-group's row
        const float* rp = x + ((size_t)b * CC + c) * LL + g * 4;

        float mx[PP] = {-INFINITY, -INFINITY, -INFINITY};
#pragma unroll
        for (int j = 0; j < 4; ++j) {
            const f32x4 v = __builtin_nontemporal_load(
                reinterpret_cast<const f32x4*>(rp + j * 64));
            const float vv[4] = {v.x, v.y, v.z, v.w};
#pragma unroll
            for (int p = 0; p < PP; ++p) {
                const float m0 = fmaxf(vv[0] + bias[p][j * 4 + 0],
                                       vv[1] + bias[p][j * 4 + 1]);
                const float m1 = fmaxf(vv[2] + bias[p][j * 4 + 2],
                                       vv[3] + bias[p][j * 4 + 3]);
                mx[p] = fmaxf(mx[p], fmaxf(m0, m1));
            }
        }

        // 4-step butterfly within the 16-lane row group (4 rows reduce
        // concurrently; 3 shfl per row vs 18 for a 64-lane reduce).
#pragma unroll
        for (int off = 8; off >= 1; off >>= 1)
#pragma unroll
            for (int p = 0; p < PP; ++p)
                mx[p] = fmaxf(mx[p], __shfl_xor(mx[p], off, 16));

        if (g == 0) {
            float* o = out + (size_t)b * (PP * CC) + c;
#pragma unroll
            for (int p = 0; p < PP; ++p)
                o[(size_t)p * CC] = mx[p];
        }
    }
}

extern "C" void kernel_launch(void* const* d_in, const int* in_sizes, int n_in,
                              void* d_out, int out_size, void* d_ws, size_t ws_size,
                              hipStream_t stream)
{
    const float* x    = (const float*)d_in[0];
    const int*   mask = (const int*)d_in[1];
    float*       out  = (float*)d_out;

    const int grid = BB * BLOCKS_PER_B;  // 4096 blocks
    piece_max_pool_kernel<<<grid, WAVES_PER_BLOCK * 64, 0, stream>>>(x, mask, out);
}